// Round 1
// baseline (1245.167 us; speedup 1.0000x reference)
//
#include <hip/hip_runtime.h>
#include <hip/hip_bf16.h>
#include <cstdint>

#define N_NODES 100000
#define N_EDGES 800000
#define CH      256
#define COUT    40
#define COUTP   48
#define EPS     1e-5f
#define SCAN_CHUNK 1024
#define NSCAN_BLK  98   // ceil(100000/1024)

typedef unsigned short u16;
typedef unsigned int   u32;
typedef short s16x8 __attribute__((ext_vector_type(8)));
typedef float f32x4 __attribute__((ext_vector_type(4)));

__device__ __forceinline__ float b2f(u32 u) { return __uint_as_float(u << 16); }
__device__ __forceinline__ u16 f2b(float f) {
    u32 u = __float_as_uint(f);
    u32 r = (u + 0x7fffu + ((u >> 16) & 1u)) >> 16;   // RNE
    return (u16)r;
}

// ---------------- CSR build ----------------
__global__ void k_count(const int* __restrict__ dst, int* __restrict__ counts) {
    int e = blockIdx.x * 256 + threadIdx.x;
    if (e < N_EDGES) atomicAdd(&counts[dst[e]], 1);
}

__global__ void k_scan1(const int* __restrict__ counts, int* __restrict__ partial,
                        int* __restrict__ blocksums) {
    __shared__ int sdata[256];
    int base = blockIdx.x * SCAN_CHUNK;
    int t = threadIdx.x;
    int v[4]; int s = 0;
    for (int j = 0; j < 4; j++) {
        int i = base + t * 4 + j;
        v[j] = (i < N_NODES) ? counts[i] : 0;
        s += v[j];
    }
    sdata[t] = s; __syncthreads();
    for (int off = 1; off < 256; off <<= 1) {
        int x = (t >= off) ? sdata[t - off] : 0;
        __syncthreads();
        sdata[t] += x;
        __syncthreads();
    }
    int incl = sdata[t];
    int run = incl - s;  // exclusive within block
    if (t == 255) blocksums[blockIdx.x] = incl;
    for (int j = 0; j < 4; j++) {
        int i = base + t * 4 + j;
        if (i < N_NODES) partial[i] = run;
        run += v[j];
    }
}

__global__ void k_scan2(int* __restrict__ blocksums) {
    __shared__ int sd[128];
    int t = threadIdx.x;
    int v = (t < NSCAN_BLK) ? blocksums[t] : 0;
    sd[t] = v; __syncthreads();
    for (int off = 1; off < 128; off <<= 1) {
        int x = (t >= off) ? sd[t - off] : 0;
        __syncthreads();
        sd[t] += x;
        __syncthreads();
    }
    if (t < NSCAN_BLK) blocksums[t] = sd[t] - v;   // exclusive
}

__global__ void k_scan3(int* __restrict__ row_start, const int* __restrict__ blocksums,
                        int* __restrict__ cursor) {
    int i = blockIdx.x * 256 + threadIdx.x;
    if (i < N_NODES) {
        int v = row_start[i] + blocksums[i >> 10];
        row_start[i] = v;
        cursor[i] = v;
    }
}

__global__ void k_fill(const int* __restrict__ src, const int* __restrict__ dst,
                       int* __restrict__ cursor, int* __restrict__ csr) {
    int e = blockIdx.x * 256 + threadIdx.x;
    if (e < N_EDGES) {
        int p = atomicAdd(&cursor[dst[e]], 1);
        csr[p] = src[e];
    }
}

__global__ void k_dis(const int* __restrict__ counts, float* __restrict__ dis) {
    int i = blockIdx.x * 256 + threadIdx.x;
    if (i < N_NODES) dis[i] = rsqrtf(1.0f + (float)counts[i]);
}

// ---------------- weight transpose + bf16 convert: Wt[n][k] = W[k][n] ----------------
__global__ void k_wt(const float* __restrict__ W, u16* __restrict__ Wt, int ncols) {
    int n = blockIdx.x, k = threadIdx.x;
    float v = (n < ncols) ? W[k * ncols + n] : 0.f;
    Wt[n * 256 + k] = f2b(v);
}

__global__ void k_xconv(const float* __restrict__ x, u16* __restrict__ xb) {
    int idx = (blockIdx.x * 256 + threadIdx.x) * 8;
    float4 a = *(const float4*)(x + idx);
    float4 b = *(const float4*)(x + idx + 4);
    u32 w0 = f2b(a.x) | ((u32)f2b(a.y) << 16);
    u32 w1 = f2b(a.z) | ((u32)f2b(a.w) << 16);
    u32 w2 = f2b(b.x) | ((u32)f2b(b.y) << 16);
    u32 w3 = f2b(b.z) | ((u32)f2b(b.w) << 16);
    uint4 o = {w0, w1, w2, w3};
    *(uint4*)(xb + idx) = o;
}

// ---------------- tiny: outv[j] = sum_k vec[k] * W[k*ncols+j] ----------------
__global__ void k_vecmat(const float* __restrict__ vec, const float* __restrict__ W,
                         int ncols, int npad, float* __restrict__ outv) {
    __shared__ float s[256];
    int t = threadIdx.x;
    s[t] = vec[t];
    __syncthreads();
    float acc = 0.f;
    if (t < ncols) {
        for (int k = 0; k < 256; k++) acc += s[k] * W[k * ncols + t];
    }
    if (t < npad) outv[t] = acc;
}

// ---------------- GEMM: Hout[N,256] = A[N,256] @ W + v2 (bf16 MFMA) ----------------
// Wt is W transposed: [256 n][256 k] bf16. Block: 256 thr, Mblk=64, each wave 64 cols.
__global__ __launch_bounds__(256) void k_gemm(const u16* __restrict__ A,
                                              const u16* __restrict__ Wt,
                                              const float* __restrict__ v2,
                                              u16* __restrict__ Hout) {
    __shared__ u16 Bs[256 * 40];   // 256 n-rows x (32+8 pad) k, 20480 B
    const int t = threadIdx.x;
    const int wave = t >> 6, lane = t & 63;
    const int lm = lane & 15, quad = lane >> 4;
    const int m0 = blockIdx.x * 64;
    const f32x4 vz = {0.f, 0.f, 0.f, 0.f};
    f32x4 acc[4][4];
    for (int m = 0; m < 4; m++)
        for (int c = 0; c < 4; c++) acc[m][c] = vz;

    for (int k0 = 0; k0 < 256; k0 += 32) {
        // stage B slice: thread t loads Wt row n=t, 32 k-values (64 B)
        {
            const uint4* srcp = (const uint4*)(Wt + t * 256 + k0);
            uint4* dl = (uint4*)(Bs + t * 40);
            dl[0] = srcp[0]; dl[1] = srcp[1]; dl[2] = srcp[2]; dl[3] = srcp[3];
        }
        __syncthreads();
        s16x8 afrag[4];
#pragma unroll
        for (int m = 0; m < 4; m++) {
            int row = m0 + m * 16 + lm;
            if (row < N_NODES) afrag[m] = *(const s16x8*)(A + row * 256 + k0 + quad * 8);
            else { s16x8 z = {0,0,0,0,0,0,0,0}; afrag[m] = z; }
        }
#pragma unroll
        for (int c = 0; c < 4; c++) {
            s16x8 bfrag = *(const s16x8*)(Bs + (wave * 64 + c * 16 + lm) * 40 + quad * 8);
#pragma unroll
            for (int m = 0; m < 4; m++)
                acc[m][c] = __builtin_amdgcn_mfma_f32_16x16x32_bf16(afrag[m], bfrag, acc[m][c], 0, 0, 0);
        }
        __syncthreads();
    }
    // epilogue: C/D layout col=lane&15, row=quad*4+i
#pragma unroll
    for (int m = 0; m < 4; m++) {
#pragma unroll
        for (int c = 0; c < 4; c++) {
            int col = wave * 64 + c * 16 + lm;
            float vv = v2[col];
#pragma unroll
            for (int i = 0; i < 4; i++) {
                int row = m0 + m * 16 + quad * 4 + i;
                if (row < N_NODES) Hout[row * 256 + col] = f2b(acc[m][c][i] + vv);
            }
        }
    }
}

// ---------------- GEMM layer 2: Hout[N,48] = A[N,256] @ W2pad + v2 ----------------
__global__ __launch_bounds__(256) void k_gemm2(const u16* __restrict__ A,
                                               const u16* __restrict__ Wt,
                                               const float* __restrict__ v2,
                                               u16* __restrict__ Hout) {
    __shared__ u16 Bs[48 * 40];
    const int t = threadIdx.x;
    const int wave = t >> 6, lane = t & 63;
    const int lm = lane & 15, quad = lane >> 4;
    const int m0 = blockIdx.x * 64;
    const f32x4 vz = {0.f, 0.f, 0.f, 0.f};
    f32x4 acc[3]; acc[0] = vz; acc[1] = vz; acc[2] = vz;

    for (int k0 = 0; k0 < 256; k0 += 32) {
        if (t < 48) {
            const uint4* srcp = (const uint4*)(Wt + t * 256 + k0);
            uint4* dl = (uint4*)(Bs + t * 40);
            dl[0] = srcp[0]; dl[1] = srcp[1]; dl[2] = srcp[2]; dl[3] = srcp[3];
        }
        __syncthreads();
        int row = m0 + wave * 16 + lm;
        s16x8 af;
        if (row < N_NODES) af = *(const s16x8*)(A + row * 256 + k0 + quad * 8);
        else { s16x8 z = {0,0,0,0,0,0,0,0}; af = z; }
#pragma unroll
        for (int c = 0; c < 3; c++) {
            s16x8 bf = *(const s16x8*)(Bs + (c * 16 + lm) * 40 + quad * 8);
            acc[c] = __builtin_amdgcn_mfma_f32_16x16x32_bf16(af, bf, acc[c], 0, 0, 0);
        }
        __syncthreads();
    }
#pragma unroll
    for (int c = 0; c < 3; c++) {
        int col = c * 16 + lm;
        float vv = v2[col];
#pragma unroll
        for (int i = 0; i < 4; i++) {
            int row = m0 + wave * 16 + quad * 4 + i;
            if (row < N_NODES) Hout[row * COUTP + col] = f2b(acc[c][i] + vv);
        }
    }
}

// ---------------- aggregation: out = sum_in coef*h2[src] + h2[n]/deg + b ----------------
__global__ __launch_bounds__(256) void k_agg(const u16* __restrict__ H2,
                                             const int* __restrict__ row_start,
                                             const int* __restrict__ counts,
                                             const int* __restrict__ csr,
                                             const float* __restrict__ dis,
                                             const float* __restrict__ bias,
                                             u16* __restrict__ OutB) {
    const int node = blockIdx.x * 4 + (threadIdx.x >> 6);
    const int lane = threadIdx.x & 63;
    const int ci = lane * 4;
    const float dn = dis[node];
    float a0 = 0, a1 = 0, a2 = 0, a3 = 0;
    const int beg = row_start[node];
    const int cnt = counts[node];
    for (int e = 0; e < cnt; e++) {
        int s = csr[beg + e];
        float cf = dis[s] * dn;
        uint2 r = *(const uint2*)(H2 + s * 256 + ci);
        a0 += cf * b2f(r.x & 0xffffu); a1 += cf * b2f(r.x >> 16);
        a2 += cf * b2f(r.y & 0xffffu); a3 += cf * b2f(r.y >> 16);
    }
    uint2 rs = *(const uint2*)(H2 + node * 256 + ci);
    float sc = dn * dn;
    a0 += sc * b2f(rs.x & 0xffffu); a1 += sc * b2f(rs.x >> 16);
    a2 += sc * b2f(rs.y & 0xffffu); a3 += sc * b2f(rs.y >> 16);
    float4 bb = *(const float4*)(bias + ci);
    u32 p0 = (u32)f2b(a0 + bb.x) | ((u32)f2b(a1 + bb.y) << 16);
    u32 p1 = (u32)f2b(a2 + bb.z) | ((u32)f2b(a3 + bb.w) << 16);
    uint2 o; o.x = p0; o.y = p1;
    *(uint2*)(OutB + node * 256 + ci) = o;
}

// ---------------- BN stats: column sums / sumsq ----------------
__global__ void k_stats(const u16* __restrict__ OutB, float* __restrict__ stats) {
    int c = threadIdx.x, b = blockIdx.x;
    int r0 = b * 391, r1 = min(r0 + 391, N_NODES);
    float s = 0.f, q = 0.f;
    for (int r = r0; r < r1; r++) {
        float v = b2f(OutB[r * 256 + c]);
        s += v; q += v * v;
    }
    atomicAdd(&stats[c], s);
    atomicAdd(&stats[256 + c], q);
}

// ---------------- BN apply + ReLU + pool ----------------
__global__ void k_bnrelu(const u16* __restrict__ OutB, const float* __restrict__ stats,
                         const float* __restrict__ g, const float* __restrict__ bb,
                         u16* __restrict__ Hr, float* __restrict__ pool) {
    int c = threadIdx.x, b = blockIdx.x;
    const float inv = 1.0f / (float)N_NODES;
    float mu = stats[c] * inv;
    float var = stats[256 + c] * inv - mu * mu;
    float rs = rsqrtf(var + EPS);
    float gg = g[c] * rs;
    float bc = bb[c] - mu * gg;
    int r0 = b * 391, r1 = min(r0 + 391, N_NODES);
    float ps = 0.f;
    for (int r = r0; r < r1; r++) {
        float v = b2f(OutB[r * 256 + c]) * gg + bc;
        v = fmaxf(v, 0.f);
        ps += v;
        Hr[r * 256 + c] = f2b(v);
    }
    atomicAdd(&pool[c], ps);
}

// ---------------- virtual node update + v2_next = vx_new @ Wnext ----------------
__global__ void k_vx(const float* __restrict__ pool, const float* __restrict__ vx_old,
                     const float* __restrict__ vnW, const float* __restrict__ vnb,
                     const float* __restrict__ lng, const float* __restrict__ lnb,
                     float* __restrict__ vx_new,
                     const float* __restrict__ Wnext, int ncn, int npn,
                     float* __restrict__ v2n) {
    __shared__ float s[256];
    __shared__ float red[256];
    int t = threadIdx.x;
    s[t] = pool[t] + vx_old[t];
    __syncthreads();
    float y = vnb[t];
    for (int k = 0; k < 256; k++) y += s[k] * vnW[k * 256 + t];
    // LayerNorm over 256
    red[t] = y; __syncthreads();
    for (int off = 128; off > 0; off >>= 1) {
        if (t < off) red[t] += red[t + off];
        __syncthreads();
    }
    float mu = red[0] * (1.f / 256.f);
    __syncthreads();
    float d = y - mu;
    red[t] = d * d; __syncthreads();
    for (int off = 128; off > 0; off >>= 1) {
        if (t < off) red[t] += red[t + off];
        __syncthreads();
    }
    float var = red[0] * (1.f / 256.f);
    float v = fmaxf(d * rsqrtf(var + EPS) * lng[t] + lnb[t], 0.f);
    vx_new[t] = v;
    __syncthreads();
    s[t] = v;
    __syncthreads();
    float acc = 0.f;
    if (t < ncn) {
        for (int k = 0; k < 256; k++) acc += s[k] * Wnext[k * ncn + t];
    }
    if (t < npn) v2n[t] = acc;
}

// ---------------- layer-2 aggregation + log_softmax ----------------
__global__ __launch_bounds__(256) void k_agg2(const u16* __restrict__ H2,
                                              const int* __restrict__ row_start,
                                              const int* __restrict__ counts,
                                              const int* __restrict__ csr,
                                              const float* __restrict__ dis,
                                              const float* __restrict__ bias,
                                              float* __restrict__ OutF) {
    const int node = blockIdx.x * 4 + (threadIdx.x >> 6);
    const int lane = threadIdx.x & 63;
    const bool act = lane < COUT;
    const float dn = dis[node];
    float a = 0.f;
    int beg = row_start[node], cnt = counts[node];
    for (int e = 0; e < cnt; e++) {
        int s = csr[beg + e];
        float cf = dis[s] * dn;
        if (act) a += cf * b2f(H2[s * COUTP + lane]);
    }
    float h = 0.f;
    if (act) h = a + dn * dn * b2f(H2[node * COUTP + lane]) + bias[lane];
    float m = act ? h : -3.0e38f;
#pragma unroll
    for (int off = 32; off > 0; off >>= 1) m = fmaxf(m, __shfl_xor(m, off));
    float ex = act ? expf(h - m) : 0.f;
    float se = ex;
#pragma unroll
    for (int off = 32; off > 0; off >>= 1) se += __shfl_xor(se, off);
    if (act) OutF[node * COUT + lane] = (h - m) - logf(se);
}

extern "C" void kernel_launch(void* const* d_in, const int* in_sizes, int n_in,
                              void* d_out, int out_size, void* d_ws, size_t ws_size,
                              hipStream_t stream) {
    const float* x   = (const float*)d_in[0];
    const int*   ei  = (const int*)d_in[1];
    const int*   esrc = ei;
    const int*   edst = ei + N_EDGES;
    const float* W0 = (const float*)d_in[2];  const float* b0 = (const float*)d_in[3];
    const float* W1 = (const float*)d_in[4];  const float* b1 = (const float*)d_in[5];
    const float* W2 = (const float*)d_in[6];  const float* b2 = (const float*)d_in[7];
    const float* bg0 = (const float*)d_in[8]; const float* bb0 = (const float*)d_in[9];
    const float* bg1 = (const float*)d_in[10]; const float* bb1 = (const float*)d_in[11];
    const float* vn_emb = (const float*)d_in[12];
    const float* vW0 = (const float*)d_in[13]; const float* vb0 = (const float*)d_in[14];
    const float* lg0 = (const float*)d_in[15]; const float* lb0 = (const float*)d_in[16];
    const float* vW1 = (const float*)d_in[17]; const float* vb1 = (const float*)d_in[18];
    const float* lg1 = (const float*)d_in[19]; const float* lb1 = (const float*)d_in[20];

    char* w = (char*)d_ws;
    auto alloc = [&](size_t bytes) { void* p = (void*)w; w += ((bytes + 255) / 256) * 256; return p; };
    u16* H2    = (u16*)alloc((size_t)N_NODES * 256 * 2);   // h@W + v2 (bf16); reused as [N,48] in layer2
    u16* HR    = (u16*)alloc((size_t)N_NODES * 256 * 2);   // xb, then relu(bn()) outputs (bf16)
    u16* OutB  = (u16*)alloc((size_t)N_NODES * 256 * 2);   // GCN output pre-BN (bf16)
    int* csr   = (int*)alloc((size_t)N_EDGES * 4);
    int* counts = (int*)alloc((size_t)N_NODES * 4);
    int* rowst  = (int*)alloc((size_t)N_NODES * 4);
    int* cursor = (int*)alloc((size_t)N_NODES * 4);
    float* dis  = (float*)alloc((size_t)N_NODES * 4);
    u16* Wtb0 = (u16*)alloc(256 * 256 * 2);
    u16* Wtb1 = (u16*)alloc(256 * 256 * 2);
    u16* Wt2b = (u16*)alloc(COUTP * 256 * 2);
    int* scanblk = (int*)alloc(128 * 4);
    float* stats = (float*)alloc(768 * 4);   // sum[256], sumsq[256], pool[256]
    float* vxA = (float*)alloc(256 * 4);
    float* vxB = (float*)alloc(256 * 4);
    float* v20 = (float*)alloc(256 * 4);
    float* v21 = (float*)alloc(256 * 4);
    float* v22 = (float*)alloc(64 * 4);
    (void)ws_size; (void)in_sizes; (void)n_in; (void)out_size;

    // ---- graph prep: degrees + CSR ----
    hipMemsetAsync(counts, 0, (size_t)N_NODES * 4, stream);
    k_count<<<(N_EDGES + 255) / 256, 256, 0, stream>>>(edst, counts);
    k_scan1<<<NSCAN_BLK, 256, 0, stream>>>(counts, rowst, scanblk);
    k_scan2<<<1, 128, 0, stream>>>(scanblk);
    k_scan3<<<(N_NODES + 255) / 256, 256, 0, stream>>>(rowst, scanblk, cursor);
    k_fill<<<(N_EDGES + 255) / 256, 256, 0, stream>>>(esrc, edst, cursor, csr);
    k_dis<<<(N_NODES + 255) / 256, 256, 0, stream>>>(counts, dis);

    // ---- weight prep ----
    k_wt<<<256, 256, 0, stream>>>(W0, Wtb0, 256);
    k_wt<<<256, 256, 0, stream>>>(W1, Wtb1, 256);
    k_wt<<<COUTP, 256, 0, stream>>>(W2, Wt2b, COUT);
    k_xconv<<<(N_NODES * 256 / 8 + 255) / 256, 256, 0, stream>>>(x, HR);
    k_vecmat<<<1, 256, 0, stream>>>(vn_emb, W0, 256, 256, v20);   // v2_0 = vx0 @ W0

    // ---- layer 0 ----
    k_gemm<<<(N_NODES + 63) / 64, 256, 0, stream>>>(HR, Wtb0, v20, H2);
    k_agg<<<N_NODES / 4, 256, 0, stream>>>(H2, rowst, counts, csr, dis, b0, OutB);
    hipMemsetAsync(stats, 0, 768 * 4, stream);
    k_stats<<<256, 256, 0, stream>>>(OutB, stats);
    k_bnrelu<<<256, 256, 0, stream>>>(OutB, stats, bg0, bb0, HR, stats + 512);
    k_vx<<<1, 256, 0, stream>>>(stats + 512, vn_emb, vW0, vb0, lg0, lb0, vxA, W1, 256, 256, v21);

    // ---- layer 1 ----
    k_gemm<<<(N_NODES + 63) / 64, 256, 0, stream>>>(HR, Wtb1, v21, H2);
    k_agg<<<N_NODES / 4, 256, 0, stream>>>(H2, rowst, counts, csr, dis, b1, OutB);
    hipMemsetAsync(stats, 0, 768 * 4, stream);
    k_stats<<<256, 256, 0, stream>>>(OutB, stats);
    k_bnrelu<<<256, 256, 0, stream>>>(OutB, stats, bg1, bb1, HR, stats + 512);
    k_vx<<<1, 256, 0, stream>>>(stats + 512, vxA, vW1, vb1, lg1, lb1, vxB, W2, COUT, COUTP, v22);

    // ---- layer 2 + log_softmax ----
    k_gemm2<<<(N_NODES + 63) / 64, 256, 0, stream>>>(HR, Wt2b, v22, H2);
    k_agg2<<<N_NODES / 4, 256, 0, stream>>>(H2, rowst, counts, csr, dis, b2, (float*)d_out);
}

// Round 2
// 887.085 us; speedup vs baseline: 1.4037x; 1.4037x over previous
//
#include <hip/hip_runtime.h>
#include <hip/hip_bf16.h>
#include <cstdint>

#define N_NODES 100000
#define N_EDGES 800000
#define CH      256
#define COUT    40
#define COUTP   48
#define EPS     1e-5f
#define SCAN_CHUNK 1024
#define NSCAN_BLK  98   // ceil(100000/1024)
#define SB_NBLK 500
#define SB_ROWS 200     // 500*200 = 100000 exactly

typedef unsigned short u16;
typedef unsigned int   u32;
typedef short s16x8 __attribute__((ext_vector_type(8)));
typedef float f32x4 __attribute__((ext_vector_type(4)));

__device__ __forceinline__ float b2f(u32 u) { return __uint_as_float(u << 16); }
__device__ __forceinline__ u16 f2b(float f) {
    u32 u = __float_as_uint(f);
    u32 r = (u + 0x7fffu + ((u >> 16) & 1u)) >> 16;   // RNE
    return (u16)r;
}
__device__ __forceinline__ u32 packb(float a, float b) {
    return (u32)f2b(a) | ((u32)f2b(b) << 16);
}
__device__ __forceinline__ void unpack8(uint4 v, float* f) {
    f[0] = b2f(v.x & 0xffffu); f[1] = b2f(v.x >> 16);
    f[2] = b2f(v.y & 0xffffu); f[3] = b2f(v.y >> 16);
    f[4] = b2f(v.z & 0xffffu); f[5] = b2f(v.z >> 16);
    f[6] = b2f(v.w & 0xffffu); f[7] = b2f(v.w >> 16);
}

// ---------------- CSR build ----------------
__global__ void k_count(const int* __restrict__ dst, int* __restrict__ counts) {
    int e = blockIdx.x * 256 + threadIdx.x;
    if (e < N_EDGES) atomicAdd(&counts[dst[e]], 1);
}

__global__ void k_scan1(const int* __restrict__ counts, int* __restrict__ partial,
                        int* __restrict__ blocksums) {
    __shared__ int sdata[256];
    int base = blockIdx.x * SCAN_CHUNK;
    int t = threadIdx.x;
    int v[4]; int s = 0;
    for (int j = 0; j < 4; j++) {
        int i = base + t * 4 + j;
        v[j] = (i < N_NODES) ? counts[i] : 0;
        s += v[j];
    }
    sdata[t] = s; __syncthreads();
    for (int off = 1; off < 256; off <<= 1) {
        int x = (t >= off) ? sdata[t - off] : 0;
        __syncthreads();
        sdata[t] += x;
        __syncthreads();
    }
    int incl = sdata[t];
    int run = incl - s;  // exclusive within block
    if (t == 255) blocksums[blockIdx.x] = incl;
    for (int j = 0; j < 4; j++) {
        int i = base + t * 4 + j;
        if (i < N_NODES) partial[i] = run;
        run += v[j];
    }
}

__global__ void k_scan2(int* __restrict__ blocksums) {
    __shared__ int sd[128];
    int t = threadIdx.x;
    int v = (t < NSCAN_BLK) ? blocksums[t] : 0;
    sd[t] = v; __syncthreads();
    for (int off = 1; off < 128; off <<= 1) {
        int x = (t >= off) ? sd[t - off] : 0;
        __syncthreads();
        sd[t] += x;
        __syncthreads();
    }
    if (t < NSCAN_BLK) blocksums[t] = sd[t] - v;   // exclusive
}

__global__ void k_scan3(int* __restrict__ row_start, const int* __restrict__ blocksums,
                        int* __restrict__ cursor) {
    int i = blockIdx.x * 256 + threadIdx.x;
    if (i < N_NODES) {
        int v = row_start[i] + blocksums[i >> 10];
        row_start[i] = v;
        cursor[i] = v;
    }
}

__global__ void k_dis(const int* __restrict__ counts, float* __restrict__ dis) {
    int i = blockIdx.x * 256 + threadIdx.x;
    if (i < N_NODES) dis[i] = rsqrtf(1.0f + (float)counts[i]);
}

__global__ void k_fill(const int* __restrict__ src, const int* __restrict__ dst,
                       int* __restrict__ cursor, int* __restrict__ csr,
                       const float* __restrict__ dis, float* __restrict__ coefv) {
    int e = blockIdx.x * 256 + threadIdx.x;
    if (e < N_EDGES) {
        int d = dst[e], s = src[e];
        int p = atomicAdd(&cursor[d], 1);
        csr[p] = s;
        coefv[p] = dis[s] * dis[d];
    }
}

// ---------------- weight transpose + bf16 convert: Wt[n][k] = W[k][n] ----------------
__global__ void k_wt(const float* __restrict__ W, u16* __restrict__ Wt, int ncols) {
    int n = blockIdx.x, k = threadIdx.x;
    float v = (n < ncols) ? W[k * ncols + n] : 0.f;
    Wt[n * 256 + k] = f2b(v);
}

__global__ void k_xconv(const float* __restrict__ x, u16* __restrict__ xb) {
    int idx = (blockIdx.x * 256 + threadIdx.x) * 8;
    float4 a = *(const float4*)(x + idx);
    float4 b = *(const float4*)(x + idx + 4);
    uint4 o = {packb(a.x, a.y), packb(a.z, a.w), packb(b.x, b.y), packb(b.z, b.w)};
    *(uint4*)(xb + idx) = o;
}

// ---------------- tiny: outv[j] = sum_k vec[k] * W[k*ncols+j] ----------------
__global__ void k_vecmat(const float* __restrict__ vec, const float* __restrict__ W,
                         int ncols, int npad, float* __restrict__ outv) {
    __shared__ float s[256];
    int t = threadIdx.x;
    s[t] = vec[t];
    __syncthreads();
    float acc = 0.f;
    if (t < ncols) {
        for (int k = 0; k < 256; k++) acc += s[k] * W[k * ncols + t];
    }
    if (t < npad) outv[t] = acc;
}

// ---------------- GEMM: Hout[N,256] = A[N,256] @ W + v2 (bf16 MFMA) ----------------
__global__ __launch_bounds__(256) void k_gemm(const u16* __restrict__ A,
                                              const u16* __restrict__ Wt,
                                              const float* __restrict__ v2,
                                              u16* __restrict__ Hout) {
    __shared__ u16 Bs[256 * 40];   // 256 n-rows x (32+8 pad) k, 20480 B
    const int t = threadIdx.x;
    const int wave = t >> 6, lane = t & 63;
    const int lm = lane & 15, quad = lane >> 4;
    const int m0 = blockIdx.x * 64;
    const f32x4 vz = {0.f, 0.f, 0.f, 0.f};
    f32x4 acc[4][4];
    for (int m = 0; m < 4; m++)
        for (int c = 0; c < 4; c++) acc[m][c] = vz;

    for (int k0 = 0; k0 < 256; k0 += 32) {
        {
            const uint4* srcp = (const uint4*)(Wt + t * 256 + k0);
            uint4* dl = (uint4*)(Bs + t * 40);
            dl[0] = srcp[0]; dl[1] = srcp[1]; dl[2] = srcp[2]; dl[3] = srcp[3];
        }
        __syncthreads();
        s16x8 afrag[4];
#pragma unroll
        for (int m = 0; m < 4; m++) {
            int row = m0 + m * 16 + lm;
            if (row < N_NODES) afrag[m] = *(const s16x8*)(A + row * 256 + k0 + quad * 8);
            else { s16x8 z = {0,0,0,0,0,0,0,0}; afrag[m] = z; }
        }
#pragma unroll
        for (int c = 0; c < 4; c++) {
            s16x8 bfrag = *(const s16x8*)(Bs + (wave * 64 + c * 16 + lm) * 40 + quad * 8);
#pragma unroll
            for (int m = 0; m < 4; m++)
                acc[m][c] = __builtin_amdgcn_mfma_f32_16x16x32_bf16(afrag[m], bfrag, acc[m][c], 0, 0, 0);
        }
        __syncthreads();
    }
#pragma unroll
    for (int m = 0; m < 4; m++) {
#pragma unroll
        for (int c = 0; c < 4; c++) {
            int col = wave * 64 + c * 16 + lm;
            float vv = v2[col];
#pragma unroll
            for (int i = 0; i < 4; i++) {
                int row = m0 + m * 16 + quad * 4 + i;
                if (row < N_NODES) Hout[row * 256 + col] = f2b(acc[m][c][i] + vv);
            }
        }
    }
}

// ---------------- GEMM layer 2: Hout[N,48] = A[N,256] @ W2pad + v2 ----------------
__global__ __launch_bounds__(256) void k_gemm2(const u16* __restrict__ A,
                                               const u16* __restrict__ Wt,
                                               const float* __restrict__ v2,
                                               u16* __restrict__ Hout) {
    __shared__ u16 Bs[48 * 40];
    const int t = threadIdx.x;
    const int wave = t >> 6, lane = t & 63;
    const int lm = lane & 15, quad = lane >> 4;
    const int m0 = blockIdx.x * 64;
    const f32x4 vz = {0.f, 0.f, 0.f, 0.f};
    f32x4 acc[3]; acc[0] = vz; acc[1] = vz; acc[2] = vz;

    for (int k0 = 0; k0 < 256; k0 += 32) {
        if (t < 48) {
            const uint4* srcp = (const uint4*)(Wt + t * 256 + k0);
            uint4* dl = (uint4*)(Bs + t * 40);
            dl[0] = srcp[0]; dl[1] = srcp[1]; dl[2] = srcp[2]; dl[3] = srcp[3];
        }
        __syncthreads();
        int row = m0 + wave * 16 + lm;
        s16x8 af;
        if (row < N_NODES) af = *(const s16x8*)(A + row * 256 + k0 + quad * 8);
        else { s16x8 z = {0,0,0,0,0,0,0,0}; af = z; }
#pragma unroll
        for (int c = 0; c < 3; c++) {
            s16x8 bf = *(const s16x8*)(Bs + (c * 16 + lm) * 40 + quad * 8);
            acc[c] = __builtin_amdgcn_mfma_f32_16x16x32_bf16(af, bf, acc[c], 0, 0, 0);
        }
        __syncthreads();
    }
#pragma unroll
    for (int c = 0; c < 3; c++) {
        int col = c * 16 + lm;
        float vv = v2[col];
#pragma unroll
        for (int i = 0; i < 4; i++) {
            int row = m0 + wave * 16 + quad * 4 + i;
            if (row < N_NODES) Hout[row * COUTP + col] = f2b(acc[c][i] + vv);
        }
    }
}

// ---------------- aggregation: out = sum_in coef*h2[src] + h2[n]/deg + b ----------------
__global__ __launch_bounds__(256) void k_agg(const u16* __restrict__ H2,
                                             const int* __restrict__ row_start,
                                             const int* __restrict__ counts,
                                             const int* __restrict__ csr,
                                             const float* __restrict__ coefv,
                                             const float* __restrict__ dis,
                                             const float* __restrict__ bias,
                                             u16* __restrict__ OutB) {
    const int node = blockIdx.x * 4 + (threadIdx.x >> 6);
    const int lane = threadIdx.x & 63;
    const int ci = lane * 4;
    const float dn = dis[node];
    float a0 = 0, a1 = 0, a2 = 0, a3 = 0;
    const int beg = row_start[node];
    const int cnt = counts[node];
    int s_next = 0; float c_next = 0.f;
    if (cnt > 0) { s_next = csr[beg]; c_next = coefv[beg]; }
    for (int e = 0; e < cnt; e++) {
        int s = s_next; float cf = c_next;
        if (e + 1 < cnt) { s_next = csr[beg + e + 1]; c_next = coefv[beg + e + 1]; }
        uint2 r = *(const uint2*)(H2 + s * 256 + ci);
        a0 += cf * b2f(r.x & 0xffffu); a1 += cf * b2f(r.x >> 16);
        a2 += cf * b2f(r.y & 0xffffu); a3 += cf * b2f(r.y >> 16);
    }
    uint2 rs = *(const uint2*)(H2 + node * 256 + ci);
    float sc = dn * dn;
    a0 += sc * b2f(rs.x & 0xffffu); a1 += sc * b2f(rs.x >> 16);
    a2 += sc * b2f(rs.y & 0xffffu); a3 += sc * b2f(rs.y >> 16);
    float4 bb = *(const float4*)(bias + ci);
    uint2 o; o.x = packb(a0 + bb.x, a1 + bb.y); o.y = packb(a2 + bb.z, a3 + bb.w);
    *(uint2*)(OutB + node * 256 + ci) = o;
}

// ---------------- BN stats: column sums / sumsq (vectorized) ----------------
__global__ __launch_bounds__(256) void k_stats(const u16* __restrict__ OutB,
                                               float* __restrict__ stats) {
    __shared__ float lsum[256], lq[256];
    const int t = threadIdx.x;
    const int cg = (t & 31) * 8;   // channel base, 8 channels/thread
    const int rg = t >> 5;         // row subgroup 0..7
    const int r0 = blockIdx.x * SB_ROWS + rg;
    float s[8], q[8];
#pragma unroll
    for (int j = 0; j < 8; j++) { s[j] = 0.f; q[j] = 0.f; }
#pragma unroll 4
    for (int it = 0; it < SB_ROWS / 8; it++) {
        int r = r0 + it * 8;
        uint4 v = *(const uint4*)(OutB + (size_t)r * 256 + cg);
        float f[8]; unpack8(v, f);
#pragma unroll
        for (int j = 0; j < 8; j++) { s[j] += f[j]; q[j] += f[j] * f[j]; }
    }
    lsum[t] = 0.f; lq[t] = 0.f;
    __syncthreads();
#pragma unroll
    for (int j = 0; j < 8; j++) {
        atomicAdd(&lsum[cg + j], s[j]);
        atomicAdd(&lq[cg + j], q[j]);
    }
    __syncthreads();
    atomicAdd(&stats[t], lsum[t]);
    atomicAdd(&stats[256 + t], lq[t]);
}

// ---------------- BN apply + ReLU + pool (vectorized) ----------------
__global__ __launch_bounds__(256) void k_bnrelu(const u16* __restrict__ OutB,
                                                const float* __restrict__ stats,
                                                const float* __restrict__ g,
                                                const float* __restrict__ bb,
                                                u16* __restrict__ Hr,
                                                float* __restrict__ pool) {
    __shared__ float lp[256];
    const int t = threadIdx.x;
    const int cg = (t & 31) * 8;
    const int rg = t >> 5;
    const int r0 = blockIdx.x * SB_ROWS + rg;
    const float inv = 1.0f / (float)N_NODES;
    float gg[8], bc[8];
#pragma unroll
    for (int j = 0; j < 8; j++) {
        float mu = stats[cg + j] * inv;
        float var = stats[256 + cg + j] * inv - mu * mu;
        float rs = rsqrtf(var + EPS);
        gg[j] = g[cg + j] * rs;
        bc[j] = bb[cg + j] - mu * gg[j];
    }
    float ps[8];
#pragma unroll
    for (int j = 0; j < 8; j++) ps[j] = 0.f;
#pragma unroll 2
    for (int it = 0; it < SB_ROWS / 8; it++) {
        int r = r0 + it * 8;
        uint4 v = *(const uint4*)(OutB + (size_t)r * 256 + cg);
        float f[8]; unpack8(v, f);
#pragma unroll
        for (int j = 0; j < 8; j++) {
            f[j] = fmaxf(f[j] * gg[j] + bc[j], 0.f);
            ps[j] += f[j];
        }
        uint4 o = {packb(f[0], f[1]), packb(f[2], f[3]), packb(f[4], f[5]), packb(f[6], f[7])};
        *(uint4*)(Hr + (size_t)r * 256 + cg) = o;
    }
    lp[t] = 0.f;
    __syncthreads();
#pragma unroll
    for (int j = 0; j < 8; j++) atomicAdd(&lp[cg + j], ps[j]);
    __syncthreads();
    atomicAdd(&pool[t], lp[t]);
}

// ---------------- virtual node update + v2_next = vx_new @ Wnext ----------------
__global__ void k_vx(const float* __restrict__ pool, const float* __restrict__ vx_old,
                     const float* __restrict__ vnW, const float* __restrict__ vnb,
                     const float* __restrict__ lng, const float* __restrict__ lnb,
                     float* __restrict__ vx_new,
                     const float* __restrict__ Wnext, int ncn, int npn,
                     float* __restrict__ v2n) {
    __shared__ float s[256];
    __shared__ float red[256];
    int t = threadIdx.x;
    s[t] = pool[t] + vx_old[t];
    __syncthreads();
    float y = vnb[t];
    for (int k = 0; k < 256; k++) y += s[k] * vnW[k * 256 + t];
    red[t] = y; __syncthreads();
    for (int off = 128; off > 0; off >>= 1) {
        if (t < off) red[t] += red[t + off];
        __syncthreads();
    }
    float mu = red[0] * (1.f / 256.f);
    __syncthreads();
    float d = y - mu;
    red[t] = d * d; __syncthreads();
    for (int off = 128; off > 0; off >>= 1) {
        if (t < off) red[t] += red[t + off];
        __syncthreads();
    }
    float var = red[0] * (1.f / 256.f);
    float v = fmaxf(d * rsqrtf(var + EPS) * lng[t] + lnb[t], 0.f);
    vx_new[t] = v;
    __syncthreads();
    s[t] = v;
    __syncthreads();
    float acc = 0.f;
    if (t < ncn) {
        for (int k = 0; k < 256; k++) acc += s[k] * Wnext[k * ncn + t];
    }
    if (t < npn) v2n[t] = acc;
}

// ---------------- layer-2 aggregation + log_softmax ----------------
__global__ __launch_bounds__(256) void k_agg2(const u16* __restrict__ H2,
                                              const int* __restrict__ row_start,
                                              const int* __restrict__ counts,
                                              const int* __restrict__ csr,
                                              const float* __restrict__ coefv,
                                              const float* __restrict__ dis,
                                              const float* __restrict__ bias,
                                              float* __restrict__ OutF) {
    const int node = blockIdx.x * 4 + (threadIdx.x >> 6);
    const int lane = threadIdx.x & 63;
    const bool act = lane < COUT;
    const float dn = dis[node];
    float a = 0.f;
    int beg = row_start[node], cnt = counts[node];
    for (int e = 0; e < cnt; e++) {
        int s = csr[beg + e];
        float cf = coefv[beg + e];
        if (act) a += cf * b2f(H2[s * COUTP + lane]);
    }
    float h = 0.f;
    if (act) h = a + dn * dn * b2f(H2[node * COUTP + lane]) + bias[lane];
    float m = act ? h : -3.0e38f;
#pragma unroll
    for (int off = 32; off > 0; off >>= 1) m = fmaxf(m, __shfl_xor(m, off));
    float ex = act ? expf(h - m) : 0.f;
    float se = ex;
#pragma unroll
    for (int off = 32; off > 0; off >>= 1) se += __shfl_xor(se, off);
    if (act) OutF[node * COUT + lane] = (h - m) - logf(se);
}

extern "C" void kernel_launch(void* const* d_in, const int* in_sizes, int n_in,
                              void* d_out, int out_size, void* d_ws, size_t ws_size,
                              hipStream_t stream) {
    const float* x   = (const float*)d_in[0];
    const int*   ei  = (const int*)d_in[1];
    const int*   esrc = ei;
    const int*   edst = ei + N_EDGES;
    const float* W0 = (const float*)d_in[2];  const float* b0 = (const float*)d_in[3];
    const float* W1 = (const float*)d_in[4];  const float* b1 = (const float*)d_in[5];
    const float* W2 = (const float*)d_in[6];  const float* b2 = (const float*)d_in[7];
    const float* bg0 = (const float*)d_in[8]; const float* bb0 = (const float*)d_in[9];
    const float* bg1 = (const float*)d_in[10]; const float* bb1 = (const float*)d_in[11];
    const float* vn_emb = (const float*)d_in[12];
    const float* vW0 = (const float*)d_in[13]; const float* vb0 = (const float*)d_in[14];
    const float* lg0 = (const float*)d_in[15]; const float* lb0 = (const float*)d_in[16];
    const float* vW1 = (const float*)d_in[17]; const float* vb1 = (const float*)d_in[18];
    const float* lg1 = (const float*)d_in[19]; const float* lb1 = (const float*)d_in[20];

    char* w = (char*)d_ws;
    auto alloc = [&](size_t bytes) { void* p = (void*)w; w += ((bytes + 255) / 256) * 256; return p; };
    u16* H2    = (u16*)alloc((size_t)N_NODES * 256 * 2);
    u16* HR    = (u16*)alloc((size_t)N_NODES * 256 * 2);
    u16* OutB  = (u16*)alloc((size_t)N_NODES * 256 * 2);
    int* csr   = (int*)alloc((size_t)N_EDGES * 4);
    float* coefv = (float*)alloc((size_t)N_EDGES * 4);
    int* counts = (int*)alloc((size_t)N_NODES * 4);
    int* rowst  = (int*)alloc((size_t)N_NODES * 4);
    int* cursor = (int*)alloc((size_t)N_NODES * 4);
    float* dis  = (float*)alloc((size_t)N_NODES * 4);
    u16* Wtb0 = (u16*)alloc(256 * 256 * 2);
    u16* Wtb1 = (u16*)alloc(256 * 256 * 2);
    u16* Wt2b = (u16*)alloc(COUTP * 256 * 2);
    int* scanblk = (int*)alloc(128 * 4);
    float* stats = (float*)alloc(768 * 4);   // sum[256], sumsq[256], pool[256]
    float* vxA = (float*)alloc(256 * 4);
    float* vxB = (float*)alloc(256 * 4);
    float* v20 = (float*)alloc(256 * 4);
    float* v21 = (float*)alloc(256 * 4);
    float* v22 = (float*)alloc(64 * 4);
    (void)ws_size; (void)in_sizes; (void)n_in; (void)out_size;

    // ---- graph prep: degrees + CSR + edge coefficients ----
    hipMemsetAsync(counts, 0, (size_t)N_NODES * 4, stream);
    k_count<<<(N_EDGES + 255) / 256, 256, 0, stream>>>(edst, counts);
    k_dis<<<(N_NODES + 255) / 256, 256, 0, stream>>>(counts, dis);
    k_scan1<<<NSCAN_BLK, 256, 0, stream>>>(counts, rowst, scanblk);
    k_scan2<<<1, 128, 0, stream>>>(scanblk);
    k_scan3<<<(N_NODES + 255) / 256, 256, 0, stream>>>(rowst, scanblk, cursor);
    k_fill<<<(N_EDGES + 255) / 256, 256, 0, stream>>>(esrc, edst, cursor, csr, dis, coefv);

    // ---- weight prep ----
    k_wt<<<256, 256, 0, stream>>>(W0, Wtb0, 256);
    k_wt<<<256, 256, 0, stream>>>(W1, Wtb1, 256);
    k_wt<<<COUTP, 256, 0, stream>>>(W2, Wt2b, COUT);
    k_xconv<<<(N_NODES * 256 / 8 + 255) / 256, 256, 0, stream>>>(x, HR);
    k_vecmat<<<1, 256, 0, stream>>>(vn_emb, W0, 256, 256, v20);

    // ---- layer 0 ----
    k_gemm<<<(N_NODES + 63) / 64, 256, 0, stream>>>(HR, Wtb0, v20, H2);
    k_agg<<<N_NODES / 4, 256, 0, stream>>>(H2, rowst, counts, csr, coefv, dis, b0, OutB);
    hipMemsetAsync(stats, 0, 768 * 4, stream);
    k_stats<<<SB_NBLK, 256, 0, stream>>>(OutB, stats);
    k_bnrelu<<<SB_NBLK, 256, 0, stream>>>(OutB, stats, bg0, bb0, HR, stats + 512);
    k_vx<<<1, 256, 0, stream>>>(stats + 512, vn_emb, vW0, vb0, lg0, lb0, vxA, W1, 256, 256, v21);

    // ---- layer 1 ----
    k_gemm<<<(N_NODES + 63) / 64, 256, 0, stream>>>(HR, Wtb1, v21, H2);
    k_agg<<<N_NODES / 4, 256, 0, stream>>>(H2, rowst, counts, csr, coefv, dis, b1, OutB);
    hipMemsetAsync(stats, 0, 768 * 4, stream);
    k_stats<<<SB_NBLK, 256, 0, stream>>>(OutB, stats);
    k_bnrelu<<<SB_NBLK, 256, 0, stream>>>(OutB, stats, bg1, bb1, HR, stats + 512);
    k_vx<<<1, 256, 0, stream>>>(stats + 512, vxA, vW1, vb1, lg1, lb1, vxB, W2, COUT, COUTP, v22);

    // ---- layer 2 + log_softmax ----
    k_gemm2<<<(N_NODES + 63) / 64, 256, 0, stream>>>(HR, Wt2b, v22, H2);
    k_agg2<<<N_NODES / 4, 256, 0, stream>>>(H2, rowst, counts, csr, coefv, dis, b2, (float*)d_out);
}

// Round 3
// 832.987 us; speedup vs baseline: 1.4948x; 1.0649x over previous
//
#include <hip/hip_runtime.h>
#include <hip/hip_bf16.h>
#include <cstdint>

#define N_NODES 100000
#define N_EDGES 800000
#define CH      256
#define COUT    40
#define COUTP   48
#define EPS     1e-5f
#define SCAN_CHUNK 1024
#define NSCAN_BLK  98   // ceil(100000/1024)
#define SB_NBLK 500
#define SB_ROWS 200     // 500*200 = 100000 exactly
#define AGG_NPW 16      // nodes per wave in k_agg

typedef unsigned short u16;
typedef unsigned int   u32;
typedef short s16x8 __attribute__((ext_vector_type(8)));
typedef float f32x4 __attribute__((ext_vector_type(4)));

__device__ __forceinline__ float b2f(u32 u) { return __uint_as_float(u << 16); }
__device__ __forceinline__ u16 f2b(float f) {
    u32 u = __float_as_uint(f);
    u32 r = (u + 0x7fffu + ((u >> 16) & 1u)) >> 16;   // RNE
    return (u16)r;
}
__device__ __forceinline__ u32 packb(float a, float b) {
    return (u32)f2b(a) | ((u32)f2b(b) << 16);
}
__device__ __forceinline__ void unpack8(uint4 v, float* f) {
    f[0] = b2f(v.x & 0xffffu); f[1] = b2f(v.x >> 16);
    f[2] = b2f(v.y & 0xffffu); f[3] = b2f(v.y >> 16);
    f[4] = b2f(v.z & 0xffffu); f[5] = b2f(v.z >> 16);
    f[6] = b2f(v.w & 0xffffu); f[7] = b2f(v.w >> 16);
}

// ---------------- CSR build ----------------
__global__ void k_count(const int* __restrict__ dst, int* __restrict__ counts) {
    int e = blockIdx.x * 256 + threadIdx.x;
    if (e < N_EDGES) atomicAdd(&counts[dst[e]], 1);
}

__global__ void k_scan1(const int* __restrict__ counts, int* __restrict__ partial,
                        int* __restrict__ blocksums) {
    __shared__ int sdata[256];
    int base = blockIdx.x * SCAN_CHUNK;
    int t = threadIdx.x;
    int v[4]; int s = 0;
    for (int j = 0; j < 4; j++) {
        int i = base + t * 4 + j;
        v[j] = (i < N_NODES) ? counts[i] : 0;
        s += v[j];
    }
    sdata[t] = s; __syncthreads();
    for (int off = 1; off < 256; off <<= 1) {
        int x = (t >= off) ? sdata[t - off] : 0;
        __syncthreads();
        sdata[t] += x;
        __syncthreads();
    }
    int incl = sdata[t];
    int run = incl - s;
    if (t == 255) blocksums[blockIdx.x] = incl;
    for (int j = 0; j < 4; j++) {
        int i = base + t * 4 + j;
        if (i < N_NODES) partial[i] = run;
        run += v[j];
    }
}

__global__ void k_scan2(int* __restrict__ blocksums) {
    __shared__ int sd[128];
    int t = threadIdx.x;
    int v = (t < NSCAN_BLK) ? blocksums[t] : 0;
    sd[t] = v; __syncthreads();
    for (int off = 1; off < 128; off <<= 1) {
        int x = (t >= off) ? sd[t - off] : 0;
        __syncthreads();
        sd[t] += x;
        __syncthreads();
    }
    if (t < NSCAN_BLK) blocksums[t] = sd[t] - v;
}

__global__ void k_scan3(int* __restrict__ row_start, const int* __restrict__ blocksums,
                        int* __restrict__ cursor) {
    int i = blockIdx.x * 256 + threadIdx.x;
    if (i < N_NODES) {
        int v = row_start[i] + blocksums[i >> 10];
        row_start[i] = v;
        cursor[i] = v;
    }
}

__global__ void k_dis(const int* __restrict__ counts, float* __restrict__ dis) {
    int i = blockIdx.x * 256 + threadIdx.x;
    if (i < N_NODES) dis[i] = rsqrtf(1.0f + (float)counts[i]);
}

__global__ void k_fill(const int* __restrict__ src, const int* __restrict__ dst,
                       int* __restrict__ cursor, int* __restrict__ csr,
                       const float* __restrict__ dis, float* __restrict__ coefv) {
    int e = blockIdx.x * 256 + threadIdx.x;
    if (e < N_EDGES) {
        int d = dst[e], s = src[e];
        int p = atomicAdd(&cursor[d], 1);
        csr[p] = s;
        coefv[p] = dis[s] * dis[d];
    }
}

// ---------------- weight transpose + bf16 convert: Wt[n][k] = W[k][n] ----------------
__global__ void k_wt(const float* __restrict__ W, u16* __restrict__ Wt, int ncols) {
    int n = blockIdx.x, k = threadIdx.x;
    float v = (n < ncols) ? W[k * ncols + n] : 0.f;
    Wt[n * 256 + k] = f2b(v);
}

__global__ void k_xconv(const float* __restrict__ x, u16* __restrict__ xb) {
    int idx = (blockIdx.x * 256 + threadIdx.x) * 8;
    float4 a = *(const float4*)(x + idx);
    float4 b = *(const float4*)(x + idx + 4);
    uint4 o = {packb(a.x, a.y), packb(a.z, a.w), packb(b.x, b.y), packb(b.z, b.w)};
    *(uint4*)(xb + idx) = o;
}

// ---------------- tiny: outv[j] = sum_k vec[k] * W[k*ncols+j] ----------------
__global__ void k_vecmat(const float* __restrict__ vec, const float* __restrict__ W,
                         int ncols, int npad, float* __restrict__ outv) {
    __shared__ float s[256];
    int t = threadIdx.x;
    s[t] = vec[t];
    __syncthreads();
    float acc = 0.f;
    if (t < ncols) {
        for (int k = 0; k < 256; k++) acc += s[k] * W[k * ncols + t];
    }
    if (t < npad) outv[t] = acc;
}

// ---------------- GEMM: Hout[N,256] = A[N,256] @ W (bf16 MFMA) ----------------
__global__ __launch_bounds__(256) void k_gemm(const u16* __restrict__ A,
                                              const u16* __restrict__ Wt,
                                              u16* __restrict__ Hout) {
    __shared__ u16 Bs[256 * 40];
    const int t = threadIdx.x;
    const int wave = t >> 6, lane = t & 63;
    const int lm = lane & 15, quad = lane >> 4;
    const int m0 = blockIdx.x * 64;
    const f32x4 vz = {0.f, 0.f, 0.f, 0.f};
    f32x4 acc[4][4];
    for (int m = 0; m < 4; m++)
        for (int c = 0; c < 4; c++) acc[m][c] = vz;

    for (int k0 = 0; k0 < 256; k0 += 32) {
        {
            const uint4* srcp = (const uint4*)(Wt + t * 256 + k0);
            uint4* dl = (uint4*)(Bs + t * 40);
            dl[0] = srcp[0]; dl[1] = srcp[1]; dl[2] = srcp[2]; dl[3] = srcp[3];
        }
        __syncthreads();
        s16x8 afrag[4];
#pragma unroll
        for (int m = 0; m < 4; m++) {
            int row = m0 + m * 16 + lm;
            if (row < N_NODES) afrag[m] = *(const s16x8*)(A + (size_t)row * 256 + k0 + quad * 8);
            else { s16x8 z = {0,0,0,0,0,0,0,0}; afrag[m] = z; }
        }
#pragma unroll
        for (int c = 0; c < 4; c++) {
            s16x8 bfrag = *(const s16x8*)(Bs + (wave * 64 + c * 16 + lm) * 40 + quad * 8);
#pragma unroll
            for (int m = 0; m < 4; m++)
                acc[m][c] = __builtin_amdgcn_mfma_f32_16x16x32_bf16(afrag[m], bfrag, acc[m][c], 0, 0, 0);
        }
        __syncthreads();
    }
#pragma unroll
    for (int m = 0; m < 4; m++) {
#pragma unroll
        for (int c = 0; c < 4; c++) {
            int col = wave * 64 + c * 16 + lm;
#pragma unroll
            for (int i = 0; i < 4; i++) {
                int row = m0 + m * 16 + quad * 4 + i;
                if (row < N_NODES) Hout[(size_t)row * 256 + col] = f2b(acc[m][c][i]);
            }
        }
    }
}

// ---------------- GEMM layer 2: Hout[N,48] = A[N,256] @ W2pad ----------------
__global__ __launch_bounds__(256) void k_gemm2(const u16* __restrict__ A,
                                               const u16* __restrict__ Wt,
                                               u16* __restrict__ Hout) {
    __shared__ u16 Bs[48 * 40];
    const int t = threadIdx.x;
    const int wave = t >> 6, lane = t & 63;
    const int lm = lane & 15, quad = lane >> 4;
    const int m0 = blockIdx.x * 64;
    const f32x4 vz = {0.f, 0.f, 0.f, 0.f};
    f32x4 acc[3]; acc[0] = vz; acc[1] = vz; acc[2] = vz;

    for (int k0 = 0; k0 < 256; k0 += 32) {
        if (t < 48) {
            const uint4* srcp = (const uint4*)(Wt + t * 256 + k0);
            uint4* dl = (uint4*)(Bs + t * 40);
            dl[0] = srcp[0]; dl[1] = srcp[1]; dl[2] = srcp[2]; dl[3] = srcp[3];
        }
        __syncthreads();
        int row = m0 + wave * 16 + lm;
        s16x8 af;
        if (row < N_NODES) af = *(const s16x8*)(A + (size_t)row * 256 + k0 + quad * 8);
        else { s16x8 z = {0,0,0,0,0,0,0,0}; af = z; }
#pragma unroll
        for (int c = 0; c < 3; c++) {
            s16x8 bf = *(const s16x8*)(Bs + (c * 16 + lm) * 40 + quad * 8);
            acc[c] = __builtin_amdgcn_mfma_f32_16x16x32_bf16(af, bf, acc[c], 0, 0, 0);
        }
        __syncthreads();
    }
#pragma unroll
    for (int c = 0; c < 3; c++) {
        int col = c * 16 + lm;
#pragma unroll
        for (int i = 0; i < 4; i++) {
            int row = m0 + wave * 16 + quad * 4 + i;
            if (row < N_NODES) Hout[(size_t)row * COUTP + col] = f2b(acc[c][i]);
        }
    }
}

// ---- aggregation L0/L1: OutB = agg(H2p) + (cs+dn^2)*v2 + b, fused BN stats ----
// 16 nodes/wave, 4-way edge unroll. grid = ceil(N/64)
__global__ __launch_bounds__(256) void k_agg(const u16* __restrict__ H2,
                                             const int* __restrict__ row_start,
                                             const int* __restrict__ counts,
                                             const int* __restrict__ csr,
                                             const float* __restrict__ coefv,
                                             const float* __restrict__ dis,
                                             const float* __restrict__ bias,
                                             const float* __restrict__ v2,
                                             u16* __restrict__ OutB,
                                             float* __restrict__ stats) {
    __shared__ float ls[512];
    const int t = threadIdx.x, wave = t >> 6, lane = t & 63, ci = lane * 4;
    const float4 bb = *(const float4*)(bias + ci);
    const float4 vv = *(const float4*)(v2 + ci);
    float s0=0,s1=0,s2=0,s3=0,q0=0,q1=0,q2=0,q3=0;
    const int nbase = blockIdx.x * (4 * AGG_NPW) + wave * AGG_NPW;
    for (int i = 0; i < AGG_NPW; i++) {
        const int node = nbase + i;
        if (node >= N_NODES) break;
        const int beg = row_start[node], cnt = counts[node];
        const float dn = dis[node];
        float a0=0,a1=0,a2=0,a3=0, cs=0;
        int e = 0;
        for (; e + 4 <= cnt; e += 4) {
            int ia = csr[beg+e], ib = csr[beg+e+1], ic = csr[beg+e+2], id = csr[beg+e+3];
            float ca = coefv[beg+e], cb = coefv[beg+e+1], cc = coefv[beg+e+2], cd = coefv[beg+e+3];
            uint2 ra = *(const uint2*)(H2 + (size_t)ia * 256 + ci);
            uint2 rb = *(const uint2*)(H2 + (size_t)ib * 256 + ci);
            uint2 rc = *(const uint2*)(H2 + (size_t)ic * 256 + ci);
            uint2 rd = *(const uint2*)(H2 + (size_t)id * 256 + ci);
            cs += ca + cb + cc + cd;
            a0 += ca*b2f(ra.x&0xffffu) + cb*b2f(rb.x&0xffffu) + cc*b2f(rc.x&0xffffu) + cd*b2f(rd.x&0xffffu);
            a1 += ca*b2f(ra.x>>16)     + cb*b2f(rb.x>>16)     + cc*b2f(rc.x>>16)     + cd*b2f(rd.x>>16);
            a2 += ca*b2f(ra.y&0xffffu) + cb*b2f(rb.y&0xffffu) + cc*b2f(rc.y&0xffffu) + cd*b2f(rd.y&0xffffu);
            a3 += ca*b2f(ra.y>>16)     + cb*b2f(rb.y>>16)     + cc*b2f(rc.y>>16)     + cd*b2f(rd.y>>16);
        }
        for (; e < cnt; e++) {
            int ia = csr[beg+e]; float ca = coefv[beg+e];
            uint2 ra = *(const uint2*)(H2 + (size_t)ia * 256 + ci);
            cs += ca;
            a0 += ca*b2f(ra.x&0xffffu); a1 += ca*b2f(ra.x>>16);
            a2 += ca*b2f(ra.y&0xffffu); a3 += ca*b2f(ra.y>>16);
        }
        uint2 rs = *(const uint2*)(H2 + (size_t)node * 256 + ci);
        const float sc = dn * dn, cv = cs + sc;
        float f0 = a0 + sc*b2f(rs.x&0xffffu) + cv*vv.x + bb.x;
        float f1 = a1 + sc*b2f(rs.x>>16)     + cv*vv.y + bb.y;
        float f2 = a2 + sc*b2f(rs.y&0xffffu) + cv*vv.z + bb.z;
        float f3 = a3 + sc*b2f(rs.y>>16)     + cv*vv.w + bb.w;
        uint2 o; o.x = packb(f0, f1); o.y = packb(f2, f3);
        *(uint2*)(OutB + (size_t)node * 256 + ci) = o;
        s0 += f0; q0 += f0*f0; s1 += f1; q1 += f1*f1;
        s2 += f2; q2 += f2*f2; s3 += f3; q3 += f3*f3;
    }
    ls[t] = 0.f; ls[256 + t] = 0.f;
    __syncthreads();
    atomicAdd(&ls[ci], s0);   atomicAdd(&ls[ci+1], s1);
    atomicAdd(&ls[ci+2], s2); atomicAdd(&ls[ci+3], s3);
    atomicAdd(&ls[256+ci], q0);   atomicAdd(&ls[256+ci+1], q1);
    atomicAdd(&ls[256+ci+2], q2); atomicAdd(&ls[256+ci+3], q3);
    __syncthreads();
    atomicAdd(&stats[t], ls[t]);
    atomicAdd(&stats[256 + t], ls[256 + t]);
}

// ---------------- finalize BN: gg/bc from stats ----------------
__global__ void k_fin(const float* __restrict__ stats, const float* __restrict__ g,
                      const float* __restrict__ bb, float* __restrict__ ggbc) {
    int t = threadIdx.x;
    const float inv = 1.0f / (float)N_NODES;
    float mu = stats[t] * inv;
    float var = stats[256 + t] * inv - mu * mu;
    float rs = rsqrtf(var + EPS);
    float gg = g[t] * rs;
    ggbc[t] = gg;
    ggbc[256 + t] = bb[t] - mu * gg;
}

// ---------------- BN apply + ReLU + pool (vectorized) ----------------
__global__ __launch_bounds__(256) void k_bnrelu(const u16* __restrict__ OutB,
                                                const float* __restrict__ ggbc,
                                                u16* __restrict__ Hr,
                                                float* __restrict__ pool) {
    __shared__ float lp[256];
    const int t = threadIdx.x;
    const int cg = (t & 31) * 8;
    const int rg = t >> 5;
    const int r0 = blockIdx.x * SB_ROWS + rg;
    float gg[8], bc[8];
    {
        float4 a = *(const float4*)(ggbc + cg);
        float4 b = *(const float4*)(ggbc + cg + 4);
        float4 c = *(const float4*)(ggbc + 256 + cg);
        float4 d = *(const float4*)(ggbc + 256 + cg + 4);
        gg[0]=a.x; gg[1]=a.y; gg[2]=a.z; gg[3]=a.w; gg[4]=b.x; gg[5]=b.y; gg[6]=b.z; gg[7]=b.w;
        bc[0]=c.x; bc[1]=c.y; bc[2]=c.z; bc[3]=c.w; bc[4]=d.x; bc[5]=d.y; bc[6]=d.z; bc[7]=d.w;
    }
    float ps[8];
#pragma unroll
    for (int j = 0; j < 8; j++) ps[j] = 0.f;
#pragma unroll 2
    for (int it = 0; it < SB_ROWS / 8; it++) {
        int r = r0 + it * 8;
        uint4 v = *(const uint4*)(OutB + (size_t)r * 256 + cg);
        float f[8]; unpack8(v, f);
#pragma unroll
        for (int j = 0; j < 8; j++) {
            f[j] = fmaxf(f[j] * gg[j] + bc[j], 0.f);
            ps[j] += f[j];
        }
        uint4 o = {packb(f[0], f[1]), packb(f[2], f[3]), packb(f[4], f[5]), packb(f[6], f[7])};
        *(uint4*)(Hr + (size_t)r * 256 + cg) = o;
    }
    lp[t] = 0.f;
    __syncthreads();
#pragma unroll
    for (int j = 0; j < 8; j++) atomicAdd(&lp[cg + j], ps[j]);
    __syncthreads();
    atomicAdd(&pool[t], lp[t]);
}

// ---------------- virtual node update + v2_next = vx_new @ Wnext ----------------
__global__ void k_vx(const float* __restrict__ pool, const float* __restrict__ vx_old,
                     const float* __restrict__ vnW, const float* __restrict__ vnb,
                     const float* __restrict__ lng, const float* __restrict__ lnb,
                     float* __restrict__ vx_new,
                     const float* __restrict__ Wnext, int ncn, int npn,
                     float* __restrict__ v2n) {
    __shared__ float s[256];
    __shared__ float red[256];
    int t = threadIdx.x;
    s[t] = pool[t] + vx_old[t];
    __syncthreads();
    float y = vnb[t];
    for (int k = 0; k < 256; k++) y += s[k] * vnW[k * 256 + t];
    red[t] = y; __syncthreads();
    for (int off = 128; off > 0; off >>= 1) {
        if (t < off) red[t] += red[t + off];
        __syncthreads();
    }
    float mu = red[0] * (1.f / 256.f);
    __syncthreads();
    float d = y - mu;
    red[t] = d * d; __syncthreads();
    for (int off = 128; off > 0; off >>= 1) {
        if (t < off) red[t] += red[t + off];
        __syncthreads();
    }
    float var = red[0] * (1.f / 256.f);
    float v = fmaxf(d * rsqrtf(var + EPS) * lng[t] + lnb[t], 0.f);
    vx_new[t] = v;
    __syncthreads();
    s[t] = v;
    __syncthreads();
    float acc = 0.f;
    if (t < ncn) {
        for (int k = 0; k < 256; k++) acc += s[k] * Wnext[k * ncn + t];
    }
    if (t < npn) v2n[t] = acc;
}

// ---- layer-2 aggregation + (cs+dn^2)*v2 fold + log_softmax ----
// 2 edges in parallel across wave halves, 4-way unroll, 4 nodes/wave. grid = N/16
__global__ __launch_bounds__(256) void k_agg2(const u16* __restrict__ H2,
                                              const int* __restrict__ row_start,
                                              const int* __restrict__ counts,
                                              const int* __restrict__ csr,
                                              const float* __restrict__ coefv,
                                              const float* __restrict__ dis,
                                              const float* __restrict__ bias,
                                              const float* __restrict__ v2,
                                              float* __restrict__ OutF) {
    const int t = threadIdx.x, wave = t >> 6, lane = t & 63;
    const int half = lane >> 5, hl = lane & 31;
    const bool gact = hl < 24;   // gather lanes (48 padded channels, 2/lane)
    const bool cact = hl < 20;   // real channel pairs (40)
    const int c0 = 2 * hl;
    float bb0 = 0.f, bb1 = 0.f, vv0 = 0.f, vv1 = 0.f;
    if (cact) {
        float2 bv = *(const float2*)(bias + c0); bb0 = bv.x; bb1 = bv.y;
        float2 vvv = *(const float2*)(v2 + c0);  vv0 = vvv.x; vv1 = vvv.y;
    }
    const int nbase = blockIdx.x * 16 + wave * 4;
    for (int i = 0; i < 4; i++) {
        const int node = nbase + i;
        const int beg = row_start[node], cnt = counts[node];
        const float dn = dis[node];
        float a0 = 0.f, a1 = 0.f, cs = 0.f;
        int e = half;
        for (; e + 6 < cnt; e += 8) {
            int ia = csr[beg+e], ib = csr[beg+e+2], ic = csr[beg+e+4], id = csr[beg+e+6];
            float ca = coefv[beg+e], cb = coefv[beg+e+2], cc = coefv[beg+e+4], cd = coefv[beg+e+6];
            u32 ra = 0, rb = 0, rc = 0, rd = 0;
            if (gact) {
                ra = *(const u32*)(H2 + (size_t)ia * COUTP + c0);
                rb = *(const u32*)(H2 + (size_t)ib * COUTP + c0);
                rc = *(const u32*)(H2 + (size_t)ic * COUTP + c0);
                rd = *(const u32*)(H2 + (size_t)id * COUTP + c0);
            }
            cs += ca + cb + cc + cd;
            a0 += ca*b2f(ra&0xffffu) + cb*b2f(rb&0xffffu) + cc*b2f(rc&0xffffu) + cd*b2f(rd&0xffffu);
            a1 += ca*b2f(ra>>16)     + cb*b2f(rb>>16)     + cc*b2f(rc>>16)     + cd*b2f(rd>>16);
        }
        for (; e < cnt; e += 2) {
            int ia = csr[beg+e]; float ca = coefv[beg+e];
            u32 ra = gact ? *(const u32*)(H2 + (size_t)ia * COUTP + c0) : 0u;
            cs += ca;
            a0 += ca*b2f(ra&0xffffu); a1 += ca*b2f(ra>>16);
        }
        // combine both halves (each processed alternating edges)
        a0 += __shfl_xor(a0, 32);
        a1 += __shfl_xor(a1, 32);
        cs += __shfl_xor(cs, 32);
        const float sc = dn * dn;
        u32 rs_ = gact ? *(const u32*)(H2 + (size_t)node * COUTP + c0) : 0u;
        float h0 = a0 + sc*b2f(rs_&0xffffu) + (cs+sc)*vv0 + bb0;
        float h1 = a1 + sc*b2f(rs_>>16)     + (cs+sc)*vv1 + bb1;
        float m = cact ? fmaxf(h0, h1) : -3.0e38f;
#pragma unroll
        for (int off = 16; off > 0; off >>= 1) m = fmaxf(m, __shfl_xor(m, off));
        float ex = cact ? (expf(h0 - m) + expf(h1 - m)) : 0.f;
        float se = ex;
#pragma unroll
        for (int off = 16; off > 0; off >>= 1) se += __shfl_xor(se, off);
        float lg = logf(se);
        if (cact && half == 0) {
            float2 o = {h0 - m - lg, h1 - m - lg};
            *(float2*)(OutF + (size_t)node * COUT + c0) = o;
        }
    }
}

extern "C" void kernel_launch(void* const* d_in, const int* in_sizes, int n_in,
                              void* d_out, int out_size, void* d_ws, size_t ws_size,
                              hipStream_t stream) {
    const float* x   = (const float*)d_in[0];
    const int*   ei  = (const int*)d_in[1];
    const int*   esrc = ei;
    const int*   edst = ei + N_EDGES;
    const float* W0 = (const float*)d_in[2];  const float* b0 = (const float*)d_in[3];
    const float* W1 = (const float*)d_in[4];  const float* b1 = (const float*)d_in[5];
    const float* W2 = (const float*)d_in[6];  const float* b2 = (const float*)d_in[7];
    const float* bg0 = (const float*)d_in[8]; const float* bb0 = (const float*)d_in[9];
    const float* bg1 = (const float*)d_in[10]; const float* bb1 = (const float*)d_in[11];
    const float* vn_emb = (const float*)d_in[12];
    const float* vW0 = (const float*)d_in[13]; const float* vb0 = (const float*)d_in[14];
    const float* lg0 = (const float*)d_in[15]; const float* lb0 = (const float*)d_in[16];
    const float* vW1 = (const float*)d_in[17]; const float* vb1 = (const float*)d_in[18];
    const float* lg1 = (const float*)d_in[19]; const float* lb1 = (const float*)d_in[20];

    char* w = (char*)d_ws;
    auto alloc = [&](size_t bytes) { void* p = (void*)w; w += ((bytes + 255) / 256) * 256; return p; };
    u16* H2    = (u16*)alloc((size_t)N_NODES * 256 * 2);
    u16* HR    = (u16*)alloc((size_t)N_NODES * 256 * 2);
    u16* OutB  = (u16*)alloc((size_t)N_NODES * 256 * 2);
    int* csr   = (int*)alloc((size_t)N_EDGES * 4);
    float* coefv = (float*)alloc((size_t)N_EDGES * 4);
    int* counts = (int*)alloc((size_t)N_NODES * 4);
    int* rowst  = (int*)alloc((size_t)N_NODES * 4);
    int* cursor = (int*)alloc((size_t)N_NODES * 4);
    float* dis  = (float*)alloc((size_t)N_NODES * 4);
    u16* Wtb0 = (u16*)alloc(256 * 256 * 2);
    u16* Wtb1 = (u16*)alloc(256 * 256 * 2);
    u16* Wt2b = (u16*)alloc(COUTP * 256 * 2);
    int* scanblk = (int*)alloc(128 * 4);
    float* stats = (float*)alloc(768 * 4);   // sum[256], sumsq[256], pool[256]
    float* ggbc  = (float*)alloc(512 * 4);   // gg[256], bc[256]
    float* vxA = (float*)alloc(256 * 4);
    float* vxB = (float*)alloc(256 * 4);
    float* v20 = (float*)alloc(256 * 4);
    float* v21 = (float*)alloc(256 * 4);
    float* v22 = (float*)alloc(64 * 4);
    (void)ws_size; (void)in_sizes; (void)n_in; (void)out_size; (void)vxB;

    // ---- graph prep: degrees + CSR + edge coefficients ----
    hipMemsetAsync(counts, 0, (size_t)N_NODES * 4, stream);
    k_count<<<(N_EDGES + 255) / 256, 256, 0, stream>>>(edst, counts);
    k_dis<<<(N_NODES + 255) / 256, 256, 0, stream>>>(counts, dis);
    k_scan1<<<NSCAN_BLK, 256, 0, stream>>>(counts, rowst, scanblk);
    k_scan2<<<1, 128, 0, stream>>>(scanblk);
    k_scan3<<<(N_NODES + 255) / 256, 256, 0, stream>>>(rowst, scanblk, cursor);
    k_fill<<<(N_EDGES + 255) / 256, 256, 0, stream>>>(esrc, edst, cursor, csr, dis, coefv);

    // ---- weight prep ----
    k_wt<<<256, 256, 0, stream>>>(W0, Wtb0, 256);
    k_wt<<<256, 256, 0, stream>>>(W1, Wtb1, 256);
    k_wt<<<COUTP, 256, 0, stream>>>(W2, Wt2b, COUT);
    k_xconv<<<(N_NODES * 256 / 8 + 255) / 256, 256, 0, stream>>>(x, HR);
    k_vecmat<<<1, 256, 0, stream>>>(vn_emb, W0, 256, 256, v20);

    const int aggblk = (N_NODES + 63) / 64;

    // ---- layer 0 ----
    k_gemm<<<(N_NODES + 63) / 64, 256, 0, stream>>>(HR, Wtb0, H2);
    hipMemsetAsync(stats, 0, 768 * 4, stream);
    k_agg<<<aggblk, 256, 0, stream>>>(H2, rowst, counts, csr, coefv, dis, b0, v20, OutB, stats);
    k_fin<<<1, 256, 0, stream>>>(stats, bg0, bb0, ggbc);
    k_bnrelu<<<SB_NBLK, 256, 0, stream>>>(OutB, ggbc, HR, stats + 512);
    k_vx<<<1, 256, 0, stream>>>(stats + 512, vn_emb, vW0, vb0, lg0, lb0, vxA, W1, 256, 256, v21);

    // ---- layer 1 ----
    k_gemm<<<(N_NODES + 63) / 64, 256, 0, stream>>>(HR, Wtb1, H2);
    hipMemsetAsync(stats, 0, 768 * 4, stream);
    k_agg<<<aggblk, 256, 0, stream>>>(H2, rowst, counts, csr, coefv, dis, b1, v21, OutB, stats);
    k_fin<<<1, 256, 0, stream>>>(stats, bg1, bb1, ggbc);
    k_bnrelu<<<SB_NBLK, 256, 0, stream>>>(OutB, ggbc, HR, stats + 512);
    k_vx<<<1, 256, 0, stream>>>(stats + 512, vxA, vW1, vb1, lg1, lb1, vxB, W2, COUT, COUTP, v22);

    // ---- layer 2 + log_softmax ----
    k_gemm2<<<(N_NODES + 63) / 64, 256, 0, stream>>>(HR, Wt2b, H2);
    k_agg2<<<N_NODES / 16, 256, 0, stream>>>(H2, rowst, counts, csr, coefv, dis, b2, v22, (float*)d_out);
}